// Round 7
// baseline (131.236 us; speedup 1.0000x reference)
//
#include <hip/hip_runtime.h>
#include <stdint.h>

#define T_ 128
#define SS 512
#define STARTT 126
#define ENDT 127

typedef float f32x4 __attribute__((ext_vector_type(4)));
typedef int   i32x8 __attribute__((ext_vector_type(8)));

__device__ __forceinline__ int fp8pk_lo(float a, float b, int old) {
  return __builtin_amdgcn_cvt_pk_fp8_f32(a, b, old, false);
}
__device__ __forceinline__ int fp8pk_hi(float a, float b, int old) {
  return __builtin_amdgcn_cvt_pk_fp8_f32(a, b, old, true);
}

// 2 waves / block: wave0 = fwd chain, wave1 = bwd chain, one batch per block.
// Each chain is fully wave-resident: u (fp8, scaled) lives in the A-fragment
// registers; per step the 128x128 matvec = 8 x mfma_scale_f32_16x16x128_f8f6f4
// (broadcast-A, scales = 1.0). Tag map: tag = 8*col + tile, so each lane's 8
// outputs are tags 8*cl..8*cl+7 -> 2 packed fp8 dwords -> A-frag rebuilt with
// 8 ds_bpermute. Exact per-step max (7 fmax + 4 shfl_xor) gives a power-of-2
// rescale with zero over/underflow risk. No LDS, no barriers in the loop.
__global__ __launch_bounds__(128)
void crf_fused(const float* __restrict__ feats,
               const int* __restrict__ tags,
               const int* __restrict__ mask,
               const float* __restrict__ trans,
               float* __restrict__ out)
{
  const int b    = blockIdx.x;
  const int tid  = threadIdx.x;
  const int lane = tid & 63;
  const int w    = tid >> 6;      // 0 fwd, 1 bwd
  const int cl   = lane & 15;
  const int g    = lane >> 4;

  __shared__ __align__(16) float tstage[T_*T_];
  __shared__ float red_s[2], red_l[2];
  __shared__ float fin_uf[T_], fin_w[T_];
  __shared__ float sc_final;
  __shared__ int ksh[2];

  const float* fb = feats + (size_t)b * (SS*T_);

  // ---------------- stage transitions ----------------
  {
    const f32x4* src = (const f32x4*)trans;
    f32x4* dst = (f32x4*)tstage;
    #pragma unroll
    for (int i = 0; i < 32; ++i) dst[tid + 128*i] = src[tid + 128*i];
  }
  __syncthreads();

  // ---------------- gold score (128-thread version, passed round 3) --------
  {
    float sc = 0.f, ln = 0.f;
    #pragma unroll
    for (int it = 0; it < 4; ++it) {
      int s = tid + 128*it;
      int cur  = tags[b*SS + s];
      int prev = s ? tags[b*SS + s - 1] : STARTT;
      float mk = (float)mask[b*SS + s];
      sc += (tstage[prev*T_ + cur] + fb[s*T_ + cur]) * mk;
      ln += mk;
    }
    #pragma unroll
    for (int off = 32; off; off >>= 1) {
      sc += __shfl_down(sc, off);
      ln += __shfl_down(ln, off);
    }
    if (lane == 0) { red_s[w] = sc; red_l[w] = ln; }
  }
  __syncthreads();
  if (tid == 0) {
    float sc = red_s[0] + red_s[1];
    float ln = red_l[0] + red_l[1];
    int L = (int)ln;
    int last = L ? tags[b*SS + L - 1] : STARTT;
    sc_final = sc + tstage[last*T_ + ENDT];
  }

  // ---------------- static B-frags: fp8(exp(Tr)), k = 32g + byte ----------
  // tile t, col cl -> output tag n = 8*cl + t.
  // fwd (reference recursion alpha'_x = f_x + LSE_y(alpha_y + Tr[x,y])):
  //   B[k=y][n=x] = exp(Tr[x, y])   (round 1/2 orientation, passed)
  // bwd: B[k=j][n=i] = exp(Tr[j, i])
  i32x8 Bt[8];
  #pragma unroll
  for (int t = 0; t < 8; ++t) {
    const int row = 8*cl + t;
    #pragma unroll
    for (int rr = 0; rr < 8; ++rr) {
      const int kk = 32*g + 4*rr;
      float v0, v1, v2, v3;
      if (w == 0) {
        v0 = tstage[row*T_ + kk+0]; v1 = tstage[row*T_ + kk+1];
        v2 = tstage[row*T_ + kk+2]; v3 = tstage[row*T_ + kk+3];
      } else {
        v0 = tstage[(kk+0)*T_ + row]; v1 = tstage[(kk+1)*T_ + row];
        v2 = tstage[(kk+2)*T_ + row]; v3 = tstage[(kk+3)*T_ + row];
      }
      Bt[t][rr] = fp8pk_hi(__expf(v2), __expf(v3),
                           fp8pk_lo(__expf(v0), __expf(v1), 0));
    }
  }

  // ---------------- feat ring (4 rows deep, 8 floats/lane/row) ------------
  const int rs = w ? -T_ : T_;
  const float* fp = fb + 8*cl + (w ? 510*T_ : T_);
  f32x4 fqa0 = *(const f32x4*)(fp), fqb0 = *(const f32x4*)(fp+4); fp += rs;
  f32x4 fqa1 = *(const f32x4*)(fp), fqb1 = *(const f32x4*)(fp+4); fp += rs;
  f32x4 fqa2 = *(const f32x4*)(fp), fqb2 = *(const f32x4*)(fp+4); fp += rs;
  f32x4 fqa3 = *(const f32x4*)(fp), fqb3 = *(const f32x4*)(fp+4); fp += rs;

  const int bp0 = (4*g+0)*4, bp1 = (4*g+1)*4, bp2 = (4*g+2)*4, bp3 = (4*g+3)*4;

  float pp[8], qq[8];
  int ksum = 0;
  i32x8 af;

  // ---------------- init (row 0 fwd / row 511 bwd) ------------------------
  if (w == 0) {
    #pragma unroll
    for (int t = 0; t < 8; ++t)
      pp[t] = __expf(fb[8*cl+t] + tstage[(8*cl+t)*T_ + STARTT]);
  } else {
    #pragma unroll
    for (int t = 0; t < 8; ++t)
      pp[t] = __expf(fb[511*T_ + 8*cl+t]);
  }

  // max -> power-of-2 rescale (exact, stored max centered at 2^7) -> fp8 ->
  // A-frag rebuild via 8 bpermutes. A dword r = tags 32g+4r..+3 =
  // {d0,d1} of source lane 4g + (r>>1).
#define FINISH() do {                                                          \
    float mx = fmaxf(fmaxf(fmaxf(pp[0],pp[1]), fmaxf(pp[2],pp[3])),            \
                     fmaxf(fmaxf(pp[4],pp[5]), fmaxf(pp[6],pp[7])));           \
    mx = fmaxf(mx, __shfl_xor(mx, 1));                                         \
    mx = fmaxf(mx, __shfl_xor(mx, 2));                                         \
    mx = fmaxf(mx, __shfl_xor(mx, 4));                                         \
    mx = fmaxf(mx, __shfl_xor(mx, 8));                                         \
    int be = (int)((__float_as_uint(mx) >> 23) & 255u);                        \
    ksum += be - 134;                                                          \
    int scf = 261 - be; scf = scf > 254 ? 254 : (scf < 1 ? 1 : scf);           \
    float scv = __uint_as_float((unsigned)scf << 23);                          \
    qq[0]=pp[0]*scv; qq[1]=pp[1]*scv; qq[2]=pp[2]*scv; qq[3]=pp[3]*scv;        \
    qq[4]=pp[4]*scv; qq[5]=pp[5]*scv; qq[6]=pp[6]*scv; qq[7]=pp[7]*scv;        \
    int d0 = fp8pk_hi(qq[2], qq[3], fp8pk_lo(qq[0], qq[1], 0));                \
    int d1 = fp8pk_hi(qq[6], qq[7], fp8pk_lo(qq[4], qq[5], 0));                \
    af[0] = __builtin_amdgcn_ds_bpermute(bp0, d0);                             \
    af[1] = __builtin_amdgcn_ds_bpermute(bp0, d1);                             \
    af[2] = __builtin_amdgcn_ds_bpermute(bp1, d0);                             \
    af[3] = __builtin_amdgcn_ds_bpermute(bp1, d1);                             \
    af[4] = __builtin_amdgcn_ds_bpermute(bp2, d0);                             \
    af[5] = __builtin_amdgcn_ds_bpermute(bp2, d1);                             \
    af[6] = __builtin_amdgcn_ds_bpermute(bp3, d0);                             \
    af[7] = __builtin_amdgcn_ds_bpermute(bp3, d1);                             \
  } while (0)

  FINISH();

#define STEP(FA, FB) do {                                                      \
    f32x4 zz = {0.f, 0.f, 0.f, 0.f};                                           \
    f32x4 c0 = __builtin_amdgcn_mfma_scale_f32_16x16x128_f8f6f4(af, Bt[0], zz, 0,0,0,127,0,127); \
    f32x4 c1 = __builtin_amdgcn_mfma_scale_f32_16x16x128_f8f6f4(af, Bt[1], zz, 0,0,0,127,0,127); \
    f32x4 c2 = __builtin_amdgcn_mfma_scale_f32_16x16x128_f8f6f4(af, Bt[2], zz, 0,0,0,127,0,127); \
    f32x4 c3 = __builtin_amdgcn_mfma_scale_f32_16x16x128_f8f6f4(af, Bt[3], zz, 0,0,0,127,0,127); \
    f32x4 c4 = __builtin_amdgcn_mfma_scale_f32_16x16x128_f8f6f4(af, Bt[4], zz, 0,0,0,127,0,127); \
    f32x4 c5 = __builtin_amdgcn_mfma_scale_f32_16x16x128_f8f6f4(af, Bt[5], zz, 0,0,0,127,0,127); \
    f32x4 c6 = __builtin_amdgcn_mfma_scale_f32_16x16x128_f8f6f4(af, Bt[6], zz, 0,0,0,127,0,127); \
    f32x4 c7 = __builtin_amdgcn_mfma_scale_f32_16x16x128_f8f6f4(af, Bt[7], zz, 0,0,0,127,0,127); \
    pp[0] = c0[0] * __expf(FA[0]);                                             \
    pp[1] = c1[0] * __expf(FA[1]);                                             \
    pp[2] = c2[0] * __expf(FA[2]);                                             \
    pp[3] = c3[0] * __expf(FA[3]);                                             \
    pp[4] = c4[0] * __expf(FB[0]);                                             \
    pp[5] = c5[0] * __expf(FB[1]);                                             \
    pp[6] = c6[0] * __expf(FB[2]);                                             \
    pp[7] = c7[0] * __expf(FB[3]);                                             \
    FA = *(const f32x4*)(fp); FB = *(const f32x4*)(fp+4); fp += rs;            \
    FINISH();                                                                  \
  } while (0)

  // steps 1..255 (fwd rows 1..255 / bwd rows 510..256); prefetch stays
  // in-bounds (fwd max row 259, bwd min row 252).
  #pragma unroll 1
  for (int k0 = 0; k0 < 63; ++k0) {
    STEP(fqa0, fqb0); STEP(fqa1, fqb1); STEP(fqa2, fqb2); STEP(fqa3, fqb3);
  }
  STEP(fqa0, fqb0); STEP(fqa1, fqb1); STEP(fqa2, fqb2);
#undef STEP

  // ---------------- epilogue ----------------
  if (lane == 0) ksh[w] = ksum;
  if (w == 0) {
    if (g == 0) {
      #pragma unroll
      for (int t = 0; t < 8; ++t) fin_uf[8*cl + t] = qq[t];
    }
  } else {
    // extra matvec: fin_w = E^T * v_stored (no feat, no scale)
    f32x4 zz = {0.f, 0.f, 0.f, 0.f};
    float st[8];
    {
      f32x4 c0 = __builtin_amdgcn_mfma_scale_f32_16x16x128_f8f6f4(af, Bt[0], zz, 0,0,0,127,0,127);
      f32x4 c1 = __builtin_amdgcn_mfma_scale_f32_16x16x128_f8f6f4(af, Bt[1], zz, 0,0,0,127,0,127);
      f32x4 c2 = __builtin_amdgcn_mfma_scale_f32_16x16x128_f8f6f4(af, Bt[2], zz, 0,0,0,127,0,127);
      f32x4 c3 = __builtin_amdgcn_mfma_scale_f32_16x16x128_f8f6f4(af, Bt[3], zz, 0,0,0,127,0,127);
      f32x4 c4 = __builtin_amdgcn_mfma_scale_f32_16x16x128_f8f6f4(af, Bt[4], zz, 0,0,0,127,0,127);
      f32x4 c5 = __builtin_amdgcn_mfma_scale_f32_16x16x128_f8f6f4(af, Bt[5], zz, 0,0,0,127,0,127);
      f32x4 c6 = __builtin_amdgcn_mfma_scale_f32_16x16x128_f8f6f4(af, Bt[6], zz, 0,0,0,127,0,127);
      f32x4 c7 = __builtin_amdgcn_mfma_scale_f32_16x16x128_f8f6f4(af, Bt[7], zz, 0,0,0,127,0,127);
      st[0]=c0[0]; st[1]=c1[0]; st[2]=c2[0]; st[3]=c3[0];
      st[4]=c4[0]; st[5]=c5[0]; st[6]=c6[0]; st[7]=c7[0];
    }
    if (g == 0) {
      #pragma unroll
      for (int t = 0; t < 8; ++t) fin_w[8*cl + t] = st[t];
    }
  }
  __syncthreads();

  if (tid < 64) {
    float d = fin_uf[tid]*fin_w[tid] + fin_uf[tid+64]*fin_w[tid+64];
    #pragma unroll
    for (int off = 32; off; off >>= 1) d += __shfl_down(d, off);
    if (tid == 0) {
      float logz = __logf(d)
                 + (float)(ksh[0] + ksh[1]) * 0.6931471805599453f
                 - 10000.0f;
      out[b] = logz - sc_final;
    }
  }
#undef FINISH
}

extern "C" void kernel_launch(void* const* d_in, const int* in_sizes, int n_in,
                              void* d_out, int out_size, void* d_ws, size_t ws_size,
                              hipStream_t stream) {
  const float* feats = (const float*)d_in[0];
  const int*   tags  = (const int*)d_in[1];
  const int*   mask  = (const int*)d_in[2];
  const float* trans = (const float*)d_in[3];
  float* out = (float*)d_out;
  hipLaunchKernelGGL(crf_fused, dim3(256), dim3(128), 0, stream,
                     feats, tags, mask, trans, out);
}

// Round 8
// 95.909 us; speedup vs baseline: 1.3683x; 1.3683x over previous
//
#include <hip/hip_runtime.h>
#include <stdint.h>

#define T_ 128
#define SS 512
#define STARTT 126
#define ENDT 127

typedef float f32x4 __attribute__((ext_vector_type(4)));
typedef int   i32x4 __attribute__((ext_vector_type(4)));
typedef int   i32x8 __attribute__((ext_vector_type(8)));

__device__ __forceinline__ int fp8pk_lo(float a, float b, int old) {
  return __builtin_amdgcn_cvt_pk_fp8_f32(a, b, old, false);
}
__device__ __forceinline__ int fp8pk_hi(float a, float b, int old) {
  return __builtin_amdgcn_cvt_pk_fp8_f32(a, b, old, true);
}

// row_ror fmax reduce within each row of 16 lanes (all lanes end with row max)
#define DPPMAX(V, CTRL) do {                                                   \
    int t_ = __builtin_amdgcn_update_dpp(0, __float_as_int(V), CTRL, 0xf, 0xf, true); \
    V = fmaxf(V, __int_as_float(t_));                                          \
  } while (0)

// 8 waves / block (2 per SIMD), one batch per block. Wave w: dir = w>>2,
// chunk cc = w&3 (owns tags 32cc..32cc+31 = 2 MFMA N-tiles). u stored fp8
// e4m3 quantized against the chunk's EXACT max; the chunk max offset vs the
// lagged global frame K goes into a per-chunk e8m0 scale byte consumed by
// mfma_scale's per-lane A-scale operand (chunk == k-block == lane group).
// 2 x mfma_scale_f32_16x16x128 per wave per step; one barrier per step.
__global__ __launch_bounds__(512)
void crf_fused(const float* __restrict__ feats,
               const int* __restrict__ tags,
               const int* __restrict__ mask,
               const float* __restrict__ trans,
               float* __restrict__ out)
{
  const int b    = blockIdx.x;
  const int tid  = threadIdx.x;
  const int lane = tid & 63;
  const int w    = tid >> 6;      // 0..7
  const int dirv = w >> 2;        // 0 fwd, 1 bwd
  const int cc   = w & 3;         // chunk (32 tags)
  const int cl   = lane & 15;
  const int g    = lane >> 4;     // k-block group

  __shared__ __align__(16) float tstage[T_ * T_];
  __shared__ float red_s[8], red_l[8];
  __shared__ float sc_final;
  __shared__ __align__(16) unsigned char ubuf8[2][2][T_];   // [dir][par][tag]
  __shared__ __align__(4)  unsigned char sbytes[2][2][4];   // per-chunk e8m0
  __shared__ int   kbufL[2][2];                             // lagged global K
  __shared__ float fin_uf[T_], fin_w[T_];
  __shared__ int   ksh[2];

  const float* fb = feats + (size_t)b * (SS * T_);

  // ---------------- stage transitions ----------------
  {
    const f32x4* src = (const f32x4*)trans;
    f32x4* dst = (f32x4*)tstage;
    #pragma unroll
    for (int i = 0; i < 8; ++i) dst[tid + 512 * i] = src[tid + 512 * i];
  }
  __syncthreads();

  // ---------------- gold score (512-thread, passed round 1) ----------------
  {
    int s = tid;
    int cur  = tags[b * SS + s];
    int prev = (s == 0) ? STARTT : tags[b * SS + s - 1];
    float mk = (float)mask[b * SS + s];
    float sc = (tstage[prev * T_ + cur] + fb[s * T_ + cur]) * mk;
    float ln = mk;
    #pragma unroll
    for (int off = 32; off; off >>= 1) {
      sc += __shfl_down(sc, off);
      ln += __shfl_down(ln, off);
    }
    if (lane == 0) { red_s[w] = sc; red_l[w] = ln; }
  }
  __syncthreads();
  if (tid == 0) {
    float sc = 0.f, ln = 0.f;
    #pragma unroll
    for (int i = 0; i < 8; ++i) { sc += red_s[i]; ln += red_l[i]; }
    int L = (int)ln;
    int last = L ? tags[b * SS + L - 1] : STARTT;
    sc_final = sc + tstage[last * T_ + ENDT];
  }

  // ---------------- static B-frags: fp8(exp(Tr)) ----------------
  // fwd: B[k=y][n=x] = exp(Tr[x,y]); bwd: B[k=x][n=y] = exp(Tr[x,y]).
  // byte j of dword r (k = 32g + 4r + j) — same linear map as round 7 (passed).
  i32x8 Bt0, Bt1;
  #pragma unroll
  for (int tt = 0; tt < 2; ++tt) {
    const int n = 32 * cc + 16 * tt + cl;
    #pragma unroll
    for (int r = 0; r < 8; ++r) {
      const int kk = 32 * g + 4 * r;
      float v0, v1, v2, v3;
      if (dirv == 0) {
        v0 = tstage[n * T_ + kk + 0]; v1 = tstage[n * T_ + kk + 1];
        v2 = tstage[n * T_ + kk + 2]; v3 = tstage[n * T_ + kk + 3];
      } else {
        v0 = tstage[(kk + 0) * T_ + n]; v1 = tstage[(kk + 1) * T_ + n];
        v2 = tstage[(kk + 2) * T_ + n]; v3 = tstage[(kk + 3) * T_ + n];
      }
      int d = fp8pk_hi(__expf(v2), __expf(v3),
                       fp8pk_lo(__expf(v0), __expf(v1), 0));
      if (tt == 0) Bt0[r] = d; else Bt1[r] = d;
    }
  }

  // ---------------- feat ring (4 deep, 2 floats/lane) ----------------
  const int tagA = 32 * cc + cl;
  const int tagB = tagA + 16;
  const int rsv = dirv ? -T_ : T_;
  const float* pr = fb + tagA + (dirv ? 510 * T_ : T_);
  float fA0 = pr[0],      fB0 = pr[16];
  float fA1 = pr[rsv],    fB1 = pr[rsv + 16];
  float fA2 = pr[2*rsv],  fB2 = pr[2*rsv + 16];
  float fA3 = pr[3*rsv],  fB3 = pr[3*rsv + 16];
  const float* fpA = pr + 4 * rsv;          // prefetch row for step 1

  int ksum = 0;
  float u0s_, u1s_;

  // ---------------- init (row 0 fwd / row 511 bwd) -> parity 1 ----------------
  {
    float u0i, u1i;
    if (dirv == 0) {
      u0i = __expf(fb[tagA] + tstage[tagA * T_ + STARTT]);
      u1i = __expf(fb[tagB] + tstage[tagB * T_ + STARTT]);
    } else {
      u0i = __expf(fb[511 * T_ + tagA]);
      u1i = __expf(fb[511 * T_ + tagB]);
    }
    float mx_ = fmaxf(fmaxf(u0i, u1i), 1e-30f);
    DPPMAX(mx_, 0x121); DPPMAX(mx_, 0x122); DPPMAX(mx_, 0x124); DPPMAX(mx_, 0x128);
    int be_ = (int)((__float_as_uint(mx_) >> 23) & 255u);
    float scv_ = __uint_as_float((unsigned)(261 - be_) << 23);
    int d_ = fp8pk_lo(u0i * scv_, u1i * scv_, 0);
    if (lane < 16) {
      ubuf8[dirv][1][32 * cc + lane]      = (unsigned char)(d_ & 255);
      ubuf8[dirv][1][32 * cc + 16 + lane] = (unsigned char)((d_ >> 8) & 255);
    }
    if (lane == 0) {
      sbytes[dirv][1][cc] = (unsigned char)(be_ - 7);
      if (cc == 0) kbufL[dirv][1] = be_ - 127;
    }
    u0s_ = u0i; u1s_ = u1i;
  }
  __syncthreads();

  // ---------------- main recursion: steps 1..255 ----------------
#define STEP(KK, FRA, FRB) do {                                                \
    const int par_ = (KK) & 1;                                                 \
    const int np_  = par_ ^ 1;                                                 \
    i32x4 a0_ = *(const i32x4*)&ubuf8[dirv][par_][32 * g];                     \
    i32x4 a1_ = *(const i32x4*)&ubuf8[dirv][par_][32 * g + 16];                \
    int scl4_ = *(const int*)&sbytes[dirv][par_][0];                           \
    int Kl_   = kbufL[dirv][par_];                                             \
    float eA_ = __expf(FRA);                                                   \
    float eB_ = __expf(FRB);                                                   \
    int sb_ = (scl4_ >> (8 * g)) & 255;                                        \
    i32x8 A_;                                                                  \
    A_[0]=a0_[0]; A_[1]=a0_[1]; A_[2]=a0_[2]; A_[3]=a0_[3];                    \
    A_[4]=a1_[0]; A_[5]=a1_[1]; A_[6]=a1_[2]; A_[7]=a1_[3];                    \
    f32x4 z_ = {0.f, 0.f, 0.f, 0.f};                                           \
    f32x4 c0_ = __builtin_amdgcn_mfma_scale_f32_16x16x128_f8f6f4(              \
        A_, Bt0, z_, 0, 0, 0, sb_, 0, 127);                                    \
    f32x4 c1_ = __builtin_amdgcn_mfma_scale_f32_16x16x128_f8f6f4(              \
        A_, Bt1, z_, 0, 0, 0, sb_, 0, 127);                                    \
    float mm_ = __uint_as_float((unsigned)(127 - Kl_) << 23);                  \
    u0s_ = c0_[0] * (eA_ * mm_);                                               \
    u1s_ = c1_[0] * (eB_ * mm_);                                               \
    float mx_ = fmaxf(fmaxf(u0s_, u1s_), 1e-30f);                              \
    DPPMAX(mx_, 0x121); DPPMAX(mx_, 0x122); DPPMAX(mx_, 0x124); DPPMAX(mx_, 0x128); \
    int be_ = (int)((__float_as_uint(mx_) >> 23) & 255u);                      \
    float scv_ = __uint_as_float((unsigned)(261 - be_) << 23);                 \
    int d_ = fp8pk_lo(u0s_ * scv_, u1s_ * scv_, 0);                            \
    ksum += Kl_;                                                               \
    if (lane < 16) {                                                           \
      ubuf8[dirv][np_][32 * cc + lane]      = (unsigned char)(d_ & 255);       \
      ubuf8[dirv][np_][32 * cc + 16 + lane] = (unsigned char)((d_ >> 8) & 255);\
    }                                                                          \
    if (lane == 0) {                                                           \
      sbytes[dirv][np_][cc] = (unsigned char)(be_ - 7);                        \
      if (cc == 0) kbufL[dirv][np_] = be_ - 127;                               \
    }                                                                          \
    FRA = fpA[0]; FRB = fpA[16]; fpA += rsv;                                   \
    asm volatile("s_waitcnt lgkmcnt(0)" ::: "memory");                         \
    __builtin_amdgcn_s_barrier();                                              \
  } while (0)

  #pragma unroll 1
  for (int k0 = 1; k0 <= 249; k0 += 4) {    // steps 1..252
    STEP(1, fA0, fB0); STEP(2, fA1, fB1); STEP(3, fA2, fB2); STEP(4, fA3, fB3);
  }
  STEP(253, fA0, fB0);
  STEP(254, fA1, fB1);
  STEP(255, fA2, fB2);
#undef STEP

  // ---------------- epilogue ----------------
  if (dirv == 0) {
    if (lane < 16) {
      fin_uf[32 * cc + cl]      = u0s_;
      fin_uf[32 * cc + 16 + cl] = u1s_;
    }
    if (lane == 0 && cc == 0) ksh[0] = ksum;
  } else {
    // extra matvec: w = E^T * v_256 (parity 0 data, no feat, no recenter)
    i32x4 a0_ = *(const i32x4*)&ubuf8[1][0][32 * g];
    i32x4 a1_ = *(const i32x4*)&ubuf8[1][0][32 * g + 16];
    int scl4_ = *(const int*)&sbytes[1][0][0];
    int sb_ = (scl4_ >> (8 * g)) & 255;
    i32x8 A_;
    A_[0]=a0_[0]; A_[1]=a0_[1]; A_[2]=a0_[2]; A_[3]=a0_[3];
    A_[4]=a1_[0]; A_[5]=a1_[1]; A_[6]=a1_[2]; A_[7]=a1_[3];
    f32x4 z_ = {0.f, 0.f, 0.f, 0.f};
    f32x4 c0_ = __builtin_amdgcn_mfma_scale_f32_16x16x128_f8f6f4(
        A_, Bt0, z_, 0, 0, 0, sb_, 0, 127);
    f32x4 c1_ = __builtin_amdgcn_mfma_scale_f32_16x16x128_f8f6f4(
        A_, Bt1, z_, 0, 0, 0, sb_, 0, 127);
    if (lane < 16) {
      fin_w[32 * cc + cl]      = c0_[0];
      fin_w[32 * cc + 16 + cl] = c1_[0];
    }
    if (lane == 0 && cc == 0) ksh[1] = ksum;
  }
  __syncthreads();

  if (tid < 64) {
    float d = fin_uf[tid] * fin_w[tid] + fin_uf[tid + 64] * fin_w[tid + 64];
    #pragma unroll
    for (int off = 32; off; off >>= 1) d += __shfl_down(d, off);
    if (tid == 0) {
      float logz = __logf(d)
                 + (float)(ksh[0] + ksh[1]) * 0.6931471805599453f
                 - 10000.0f;
      out[b] = logz - sc_final;
    }
  }
}

extern "C" void kernel_launch(void* const* d_in, const int* in_sizes, int n_in,
                              void* d_out, int out_size, void* d_ws, size_t ws_size,
                              hipStream_t stream) {
  const float* feats = (const float*)d_in[0];
  const int*   tags  = (const int*)d_in[1];
  const int*   mask  = (const int*)d_in[2];
  const float* trans = (const float*)d_in[3];
  float* out = (float*)d_out;
  hipLaunchKernelGGL(crf_fused, dim3(256), dim3(512), 0, stream,
                     feats, tags, mask, trans, out);
}